// Round 6
// baseline (73.577 us; speedup 1.0000x reference)
//
#include <hip/hip_runtime.h>
#include <stdint.h>

#define NB 32
#define NM 6300
#define NC 80
#define NTOP 1000
#define NPAD 1024
#define NCAND 2048
#define NBINS 4096
#define BDT 1024

static constexpr float IMGSZ   = 320.0f;
static constexpr float CONF_TH = 0.05f;
static constexpr float NMS_TH  = 0.6f;
static constexpr float EPSF    = 1e-10f;

// ---- workspace layout (bytes) ----
static constexpr size_t OFF_SCORES = 0;                                    // f32 [NB*NM]
static constexpr size_t OFF_LABELS = OFF_SCORES + (size_t)NB * NM * 4;     // i32 [NB*NM]
static constexpr size_t OFF_NBOX   = OFF_LABELS + (size_t)NB * NM * 4;     // f32 [NB*NPAD*4]
static constexpr size_t OFF_NLAB   = OFF_NBOX   + (size_t)NB * NPAD * 16;  // i32 [NB*NPAD]
static constexpr size_t OFF_SUP    = ((OFF_NLAB + (size_t)NB * NPAD * 4) + 1023) & ~(size_t)1023; // u64 [NB*16*16*64]

// ---------------------------------------------------------------------------
// K1: per-anchor score = sigmoid(conf) * max(softmax(cls)), label = argmax.
// NOTE: numerics (lane->class map, sum order) frozen — rank ties depend on it.
// ---------------------------------------------------------------------------
__global__ __launch_bounds__(256) void k_score(const float* __restrict__ conf,
                                               const float* __restrict__ cls,
                                               float* __restrict__ scores,
                                               int* __restrict__ labels) {
#pragma clang fp contract(off)
    int t = blockIdx.x * blockDim.x + threadIdx.x;
    int a = t >> 4;          // anchor index in [0, NB*NM)
    int l = t & 15;
    if (a >= NB * NM) return;
    const float* row = cls + (size_t)a * NC;

    float v[5];
#pragma unroll
    for (int k = 0; k < 5; ++k) v[k] = row[l + 16 * k];

    float bv = v[0];
    int bi = l;
#pragma unroll
    for (int k = 1; k < 5; ++k) {
        int c = l + 16 * k;
        if (v[k] > bv) { bv = v[k]; bi = c; }
    }
#pragma unroll
    for (int m = 1; m < 16; m <<= 1) {
        float ov = __shfl_xor(bv, m, 16);
        int   oi = __shfl_xor(bi, m, 16);
        if (ov > bv || (ov == bv && oi < bi)) { bv = ov; bi = oi; }
    }
    float s = 0.0f;
#pragma unroll
    for (int k = 0; k < 5; ++k) s += expf(v[k] - bv);
#pragma unroll
    for (int m = 1; m < 16; m <<= 1) s += __shfl_xor(s, m, 16);

    if (l == 0) {
        float cf  = conf[a];
        float sig = 1.0f / (1.0f + expf(-cf));
        float inv = 1.0f / s;
        scores[a] = sig * inv;
        labels[a] = bi;
    }
}

// ---------------------------------------------------------------------------
// K2: histogram-select top-k + hybrid shfl-bitonic sort + fused decode.
// One block (1024 thr, 16 waves) per batch.
// Sort: 2 elements/thread (idx = r*1024 + tid). j<=32 phases via __shfl_xor
// (no barrier), j=1024 in-thread, j in {64..512} via LDS (14 phases only).
// Keys unique -> output identical to any correct descending sort
// (lax.top_k order: desc score, ties -> lowest index).
// ---------------------------------------------------------------------------
__global__ __launch_bounds__(BDT) void k_topk(const float* __restrict__ scores,
                                              const int* __restrict__ labels,
                                              const float* __restrict__ reg,
                                              const float* __restrict__ anchors,
                                              const float* __restrict__ stridemap,
                                              float* __restrict__ out_scores,
                                              float* __restrict__ out_labels,
                                              float* __restrict__ out_boxes,
                                              float* __restrict__ nbox,
                                              int* __restrict__ nlab) {
#pragma clang fp contract(off)
    __shared__ uint32_t hist[NBINS];    // 16 KiB
    __shared__ uint64_t key[NCAND];     // 16 KiB
    __shared__ int scnt;
    __shared__ int sT;
    int b = blockIdx.x, tid = threadIdx.x;
    const float* sb = scores + (size_t)b * NM;

    for (int i = tid; i < NBINS; i += BDT) hist[i] = 0;
    for (int i = tid; i < NCAND; i += BDT) key[i] = 0;
    if (tid == 0) scnt = 0;
    __syncthreads();

    for (int i = tid; i < NM; i += BDT)
        atomicAdd(&hist[__float_as_uint(sb[i]) >> 20], 1u);
    __syncthreads();

    if (tid < 64) {
        int l = tid;
        uint32_t q = 0;
        for (int i = 0; i < 64; ++i) q += hist[l * 64 + i];
        uint32_t s = q;
        for (int off = 1; off < 64; off <<= 1) {
            uint32_t o = __shfl_down(s, off);
            if (l + off < 64) s += o;
        }
        uint64_t m = __ballot(s >= (uint32_t)NTOP);
        int c = 63 - __clzll(m);
        uint32_t sc_ = __shfl(s, c);
        uint32_t qc  = __shfl(q, c);
        uint32_t tail = sc_ - qc;
        uint32_t v = hist[c * 64 + l];
        uint32_t s2 = v;
        for (int off = 1; off < 64; off <<= 1) {
            uint32_t o = __shfl_down(s2, off);
            if (l + off < 64) s2 += o;
        }
        uint64_t m2 = __ballot(s2 + tail >= (uint32_t)NTOP);
        int T = c * 64 + (63 - __clzll(m2));
        if (l == 0) sT = T;
    }
    __syncthreads();

    uint32_t T = (uint32_t)sT;
    int lane = tid & 63;
    for (int i = tid; i < NM; i += BDT) {
        uint32_t bits = __float_as_uint(sb[i]);
        bool pred = (bits >> 20) >= T;
        uint64_t mask = __ballot(pred);
        if (pred) {
            int leader = __ffsll((unsigned long long)mask) - 1;
            int prefix = __popcll(mask & ((1ull << lane) - 1));
            int base = 0;
            if (lane == leader) base = atomicAdd(&scnt, (int)__popcll(mask));
            base = __shfl(base, leader);
            int pos = base + prefix;
            if (pos < NCAND)
                key[pos] = ((uint64_t)bits << 32) | (uint32_t)(~(uint32_t)i);
        }
    }
    __syncthreads();

    // ---- hybrid bitonic sort, descending; element idx0 = tid, idx1 = tid+1024
    uint64_t e0 = key[tid];
    uint64_t e1 = key[tid + 1024];

#pragma unroll
    for (int kk = 2; kk <= NCAND; kk <<= 1) {
#pragma unroll
        for (int j = kk >> 1; j > 0; j >>= 1) {
            if (j == 1024) {
                // in-thread; up = true for both -> lower idx keeps max
                uint64_t mx = (e0 >= e1) ? e0 : e1;
                uint64_t mn = (e0 >= e1) ? e1 : e0;
                e0 = mx; e1 = mn;
            } else if (j >= 64) {
                // cross-wave via LDS
                __syncthreads();
                key[tid] = e0; key[tid + 1024] = e1;
                __syncthreads();
                uint64_t o0 = key[tid ^ j];
                uint64_t o1 = key[(tid + 1024) ^ j];
                bool lo  = ((tid & j) == 0);                 // same for idx1 (j<1024)
                bool up0 = ((tid & kk) == 0);
                bool up1 = (((tid + 1024) & kk) == 0);
                e0 = (lo == up0) ? ((e0 >= o0) ? e0 : o0) : ((e0 >= o0) ? o0 : e0);
                e1 = (lo == up1) ? ((e1 >= o1) ? e1 : o1) : ((e1 >= o1) ? o1 : e1);
            } else {
                // intra-wave shfl_xor
                uint64_t o0 = __shfl_xor((unsigned long long)e0, j);
                uint64_t o1 = __shfl_xor((unsigned long long)e1, j);
                bool lo  = ((lane & j) == 0);
                bool up0 = ((tid & kk) == 0);
                bool up1 = (((tid + 1024) & kk) == 0);
                e0 = (lo == up0) ? ((e0 >= o0) ? e0 : o0) : ((e0 >= o0) ? o0 : e0);
                e1 = (lo == up1) ? ((e1 >= o1) ? e1 : o1) : ((e1 >= o1) ? o1 : e1);
            }
        }
    }

    // ---- fused decode epilogue (rank tid holds e0; ranks >=1024 irrelevant)
    if (tid < NTOP) {
        uint32_t sbits = (uint32_t)(e0 >> 32);
        int idx = (int)(~(uint32_t)e0);
        out_scores[b * NTOP + tid] = __uint_as_float(sbits);
        int lab = labels[(size_t)b * NM + idx];
        out_labels[b * NTOP + tid] = (float)lab;

        const float* rg = reg + ((size_t)b * NM + idx) * 4;
        float rx = rg[0], ry = rg[1], rw = rg[2], rh = rg[3];
        const float* an = anchors + (size_t)idx * 4;
        float ax = an[0], ay = an[1], aw = an[2], ah = an[3];
        float st = stridemap[idx];

        float sx = 1.0f / (1.0f + expf(-rx));
        float sy = 1.0f / (1.0f + expf(-ry));
        float cx = ax + sx * st;
        float cy = ay + sy * st;
        float w  = aw * expf(rw);
        float h  = ah * expf(rh);
        float x1 = cx - 0.5f * w, y1 = cy - 0.5f * h;
        float x2 = cx + 0.5f * w, y2 = cy + 0.5f * h;

        float nx1 = fminf(fmaxf(x1 / IMGSZ, 0.0f), 1.0f);
        float ny1 = fminf(fmaxf(y1 / IMGSZ, 0.0f), 1.0f);
        float nx2 = fminf(fmaxf(x2 / IMGSZ, 0.0f), 1.0f);
        float ny2 = fminf(fmaxf(y2 / IMGSZ, 0.0f), 1.0f);

        float4 bx = make_float4(nx1, ny1, nx2, ny2);
        ((float4*)out_boxes)[b * NTOP + tid] = bx;
        ((float4*)nbox)[b * NPAD + tid]      = bx;
        nlab[b * NPAD + tid] = lab;
    }
}

// ---------------------------------------------------------------------------
// K4: suppression bit-matrix. One wave per 64x64 tile; lane = column j.
// Row box broadcast via __shfl with literal index (fully unrolled ->
// v_readlane, no LDS); each lane accumulates its own column word.
// sup[b][tj][ti][j0]: bit ii set iff i=ti*64+ii suppresses j=tj*64+j0.
// ---------------------------------------------------------------------------
__global__ __launch_bounds__(64) void k_supmat(const float* __restrict__ nbox,
                                               const int* __restrict__ nlab,
                                               uint64_t* __restrict__ sup) {
#pragma clang fp contract(off)
    int b = blockIdx.y;
    int t = blockIdx.x;                 // 0..135 triangular pair index
    int tj = (int)((sqrtf(8.0f * (float)t + 1.0f) - 1.0f) * 0.5f);
    while ((tj + 1) * (tj + 2) / 2 <= t) ++tj;
    while (tj * (tj + 1) / 2 > t) --tj;
    int ti = t - tj * (tj + 1) / 2;

    int lane = threadIdx.x;
    int j = tj * 64 + lane;

    float4 cj = ((const float4*)nbox)[b * NPAD + j];
    float  aj = (cj.z - cj.x) * (cj.w - cj.y);
    int    lj = nlab[b * NPAD + j];
    bool   jv = (j < NTOP);

    float4 ri = ((const float4*)nbox)[b * NPAD + ti * 64 + lane];
    float  ar = (ri.z - ri.x) * (ri.w - ri.y);
    int    rl = nlab[b * NPAD + ti * 64 + lane];

    uint32_t lobits = 0, hibits = 0;
#pragma unroll
    for (int ii = 0; ii < 64; ++ii) {
        float bix = __shfl(ri.x, ii);
        float biy = __shfl(ri.y, ii);
        float biz = __shfl(ri.z, ii);
        float biw = __shfl(ri.w, ii);
        float aiv = __shfl(ar,   ii);
        int   liv = __shfl(rl,   ii);
        int   ig  = ti * 64 + ii;
        float xx1 = fmaxf(bix, cj.x);
        float yy1 = fmaxf(biy, cj.y);
        float xx2 = fminf(biz, cj.z);
        float yy2 = fminf(biw, cj.w);
        float inter = fmaxf(EPSF, xx2 - xx1) * fmaxf(EPSF, yy2 - yy1);
        float uni   = fmaxf(aiv + aj - inter, EPSF);
        float iou   = inter / uni;
        bool pred = (ig < j) && (ig < NTOP) && jv && (liv == lj) && (iou > NMS_TH);
        if (ii < 32) lobits |= (pred ? (1u << ii) : 0u);
        else         hibits |= (pred ? (1u << (ii - 32)) : 0u);
    }
    sup[(((size_t)b * 16 + tj) * 16 + ti) * 64 + lane] =
        ((uint64_t)hibits << 32) | (uint64_t)lobits;
}

// ---------------------------------------------------------------------------
// K5: greedy NMS scan, 16 waves per batch (wave w = column-block tj=w).
// ---------------------------------------------------------------------------
__global__ __launch_bounds__(1024) void k_nms(const float* __restrict__ out_scores,
                                              const uint64_t* __restrict__ sup,
                                              float* __restrict__ out_keep) {
    __shared__ uint64_t Kw[16];
    int b    = blockIdx.x;
    int w    = threadIdx.x >> 6;    // wave id = tj block
    int lane = threadIdx.x & 63;
    const uint64_t* supb = sup + (size_t)b * 16 * 16 * 64;

    uint64_t wrow[16];
#pragma unroll
    for (int ti = 0; ti < 16; ++ti)
        wrow[ti] = (ti <= w) ? supb[((size_t)w * 16 + ti) * 64 + lane] : 0ULL;

    int pos = w * 64 + lane;
    bool k0 = (pos < NTOP) && (out_scores[b * NTOP + pos] >= CONF_TH);

    uint64_t ext = 0;
#pragma unroll
    for (int s = 0; s < 16; ++s) {
        if (w == s) {
            bool cand = k0 && (ext == 0ULL);
            uint64_t wself = wrow[s];
            uint64_t alive = __ballot(cand);
            for (int it = 0; it < 64; ++it) {
                bool dead = (wself & alive) != 0ULL;
                uint64_t na = __ballot(cand && !dead);
                if (na == alive) break;
                alive = na;
            }
            if (lane == 0) Kw[s] = alive;
            if (pos < NTOP)
                out_keep[b * NTOP + pos] = ((alive >> lane) & 1ULL) ? 1.0f : 0.0f;
        }
        __syncthreads();
        if (w > s) ext |= wrow[s] & Kw[s];
    }
}

// ---------------------------------------------------------------------------
extern "C" void kernel_launch(void* const* d_in, const int* in_sizes, int n_in,
                              void* d_out, int out_size, void* d_ws, size_t ws_size,
                              hipStream_t stream) {
    const float* conf = (const float*)d_in[0];
    const float* cls  = (const float*)d_in[1];
    const float* reg  = (const float*)d_in[2];
    const float* anch = (const float*)d_in[3];
    const float* strm = (const float*)d_in[4];

    float* out        = (float*)d_out;
    float* out_scores = out;
    float* out_labels = out + NB * NTOP;
    float* out_boxes  = out + 2 * NB * NTOP;
    float* out_keep   = out + 2 * NB * NTOP + NB * NTOP * 4;

    char* ws = (char*)d_ws;
    float*    scores = (float*)(ws + OFF_SCORES);
    int*      labels = (int*)(ws + OFF_LABELS);
    float*    nbox   = (float*)(ws + OFF_NBOX);
    int*      nlab   = (int*)(ws + OFF_NLAB);
    uint64_t* sup    = (uint64_t*)(ws + OFF_SUP);

    k_score<<<(NB * NM * 16) / 256, 256, 0, stream>>>(conf, cls, scores, labels);
    k_topk<<<NB, BDT, 0, stream>>>(scores, labels, reg, anch, strm,
                                   out_scores, out_labels, out_boxes, nbox, nlab);
    k_supmat<<<dim3(136, NB), 64, 0, stream>>>(nbox, nlab, sup);
    k_nms<<<NB, 1024, 0, stream>>>(out_scores, sup, out_keep);
}

// Round 7
// 67.733 us; speedup vs baseline: 1.0863x; 1.0863x over previous
//
#include <hip/hip_runtime.h>
#include <stdint.h>

#define NB 32
#define NM 6300
#define NC 80
#define NTOP 1000
#define NPAD 1024
#define NCAND 2048
#define NBINS 4096
#define BDT 1024

static constexpr float IMGSZ   = 320.0f;
static constexpr float CONF_TH = 0.05f;
static constexpr float NMS_TH  = 0.6f;
static constexpr float EPSF    = 1e-10f;

// ---- workspace layout (bytes) ----
static constexpr size_t OFF_SCORES = 0;                                    // f32 [NB*NM]
static constexpr size_t OFF_LABELS = OFF_SCORES + (size_t)NB * NM * 4;     // i32 [NB*NM]
static constexpr size_t OFF_NBOX   = OFF_LABELS + (size_t)NB * NM * 4;     // f32 [NB*NPAD*4]
static constexpr size_t OFF_NLAB   = OFF_NBOX   + (size_t)NB * NPAD * 16;  // i32 [NB*NPAD]
static constexpr size_t OFF_SUP    = ((OFF_NLAB + (size_t)NB * NPAD * 4) + 1023) & ~(size_t)1023; // u64 [NB*16*16*64]

// ---------------------------------------------------------------------------
// K1: per-anchor score = sigmoid(conf) * max(softmax(cls)), label = argmax.
// NOTE: numerics (lane->class map, sum order) frozen — rank ties depend on it.
// ---------------------------------------------------------------------------
__global__ __launch_bounds__(256) void k_score(const float* __restrict__ conf,
                                               const float* __restrict__ cls,
                                               float* __restrict__ scores,
                                               int* __restrict__ labels) {
#pragma clang fp contract(off)
    int t = blockIdx.x * blockDim.x + threadIdx.x;
    int a = t >> 4;          // anchor index in [0, NB*NM)
    int l = t & 15;
    if (a >= NB * NM) return;
    const float* row = cls + (size_t)a * NC;

    float v[5];
#pragma unroll
    for (int k = 0; k < 5; ++k) v[k] = row[l + 16 * k];

    float bv = v[0];
    int bi = l;
#pragma unroll
    for (int k = 1; k < 5; ++k) {
        int c = l + 16 * k;
        if (v[k] > bv) { bv = v[k]; bi = c; }
    }
#pragma unroll
    for (int m = 1; m < 16; m <<= 1) {
        float ov = __shfl_xor(bv, m, 16);
        int   oi = __shfl_xor(bi, m, 16);
        if (ov > bv || (ov == bv && oi < bi)) { bv = ov; bi = oi; }
    }
    float s = 0.0f;
#pragma unroll
    for (int k = 0; k < 5; ++k) s += expf(v[k] - bv);
#pragma unroll
    for (int m = 1; m < 16; m <<= 1) s += __shfl_xor(s, m, 16);

    if (l == 0) {
        float cf  = conf[a];
        float sig = 1.0f / (1.0f + expf(-cf));
        float inv = 1.0f / s;
        scores[a] = sig * inv;
        labels[a] = bi;
    }
}

// ---------------------------------------------------------------------------
// K2: histogram-select top-k + hybrid shfl-bitonic sort + fused decode.
// One block (1024 thr, 16 waves) per batch.
// ---------------------------------------------------------------------------
__global__ __launch_bounds__(BDT) void k_topk(const float* __restrict__ scores,
                                              const int* __restrict__ labels,
                                              const float* __restrict__ reg,
                                              const float* __restrict__ anchors,
                                              const float* __restrict__ stridemap,
                                              float* __restrict__ out_scores,
                                              float* __restrict__ out_labels,
                                              float* __restrict__ out_boxes,
                                              float* __restrict__ nbox,
                                              int* __restrict__ nlab) {
#pragma clang fp contract(off)
    __shared__ uint32_t hist[NBINS];    // 16 KiB
    __shared__ uint64_t key[NCAND];     // 16 KiB
    __shared__ int scnt;
    __shared__ int sT;
    int b = blockIdx.x, tid = threadIdx.x;
    const float* sb = scores + (size_t)b * NM;

    for (int i = tid; i < NBINS; i += BDT) hist[i] = 0;
    for (int i = tid; i < NCAND; i += BDT) key[i] = 0;
    if (tid == 0) scnt = 0;
    __syncthreads();

    for (int i = tid; i < NM; i += BDT)
        atomicAdd(&hist[__float_as_uint(sb[i]) >> 20], 1u);
    __syncthreads();

    if (tid < 64) {
        int l = tid;
        uint32_t q = 0;
        for (int i = 0; i < 64; ++i) q += hist[l * 64 + i];
        uint32_t s = q;
        for (int off = 1; off < 64; off <<= 1) {
            uint32_t o = __shfl_down(s, off);
            if (l + off < 64) s += o;
        }
        uint64_t m = __ballot(s >= (uint32_t)NTOP);
        int c = 63 - __clzll(m);
        uint32_t sc_ = __shfl(s, c);
        uint32_t qc  = __shfl(q, c);
        uint32_t tail = sc_ - qc;
        uint32_t v = hist[c * 64 + l];
        uint32_t s2 = v;
        for (int off = 1; off < 64; off <<= 1) {
            uint32_t o = __shfl_down(s2, off);
            if (l + off < 64) s2 += o;
        }
        uint64_t m2 = __ballot(s2 + tail >= (uint32_t)NTOP);
        int T = c * 64 + (63 - __clzll(m2));
        if (l == 0) sT = T;
    }
    __syncthreads();

    uint32_t T = (uint32_t)sT;
    int lane = tid & 63;
    for (int i = tid; i < NM; i += BDT) {
        uint32_t bits = __float_as_uint(sb[i]);
        bool pred = (bits >> 20) >= T;
        uint64_t mask = __ballot(pred);
        if (pred) {
            int leader = __ffsll((unsigned long long)mask) - 1;
            int prefix = __popcll(mask & ((1ull << lane) - 1));
            int base = 0;
            if (lane == leader) base = atomicAdd(&scnt, (int)__popcll(mask));
            base = __shfl(base, leader);
            int pos = base + prefix;
            if (pos < NCAND)
                key[pos] = ((uint64_t)bits << 32) | (uint32_t)(~(uint32_t)i);
        }
    }
    __syncthreads();

    // ---- hybrid bitonic sort, descending; element idx0 = tid, idx1 = tid+1024
    uint64_t e0 = key[tid];
    uint64_t e1 = key[tid + 1024];

#pragma unroll
    for (int kk = 2; kk <= NCAND; kk <<= 1) {
#pragma unroll
        for (int j = kk >> 1; j > 0; j >>= 1) {
            if (j == 1024) {
                uint64_t mx = (e0 >= e1) ? e0 : e1;
                uint64_t mn = (e0 >= e1) ? e1 : e0;
                e0 = mx; e1 = mn;
            } else if (j >= 64) {
                __syncthreads();
                key[tid] = e0; key[tid + 1024] = e1;
                __syncthreads();
                uint64_t o0 = key[tid ^ j];
                uint64_t o1 = key[(tid + 1024) ^ j];
                bool lo  = ((tid & j) == 0);
                bool up0 = ((tid & kk) == 0);
                bool up1 = (((tid + 1024) & kk) == 0);
                e0 = (lo == up0) ? ((e0 >= o0) ? e0 : o0) : ((e0 >= o0) ? o0 : e0);
                e1 = (lo == up1) ? ((e1 >= o1) ? e1 : o1) : ((e1 >= o1) ? o1 : e1);
            } else {
                uint64_t o0 = __shfl_xor((unsigned long long)e0, j);
                uint64_t o1 = __shfl_xor((unsigned long long)e1, j);
                bool lo  = ((lane & j) == 0);
                bool up0 = ((tid & kk) == 0);
                bool up1 = (((tid + 1024) & kk) == 0);
                e0 = (lo == up0) ? ((e0 >= o0) ? e0 : o0) : ((e0 >= o0) ? o0 : e0);
                e1 = (lo == up1) ? ((e1 >= o1) ? e1 : o1) : ((e1 >= o1) ? o1 : e1);
            }
        }
    }

    // ---- fused decode epilogue
    if (tid < NTOP) {
        uint32_t sbits = (uint32_t)(e0 >> 32);
        int idx = (int)(~(uint32_t)e0);
        out_scores[b * NTOP + tid] = __uint_as_float(sbits);
        int lab = labels[(size_t)b * NM + idx];
        out_labels[b * NTOP + tid] = (float)lab;

        const float* rg = reg + ((size_t)b * NM + idx) * 4;
        float rx = rg[0], ry = rg[1], rw = rg[2], rh = rg[3];
        const float* an = anchors + (size_t)idx * 4;
        float ax = an[0], ay = an[1], aw = an[2], ah = an[3];
        float st = stridemap[idx];

        float sx = 1.0f / (1.0f + expf(-rx));
        float sy = 1.0f / (1.0f + expf(-ry));
        float cx = ax + sx * st;
        float cy = ay + sy * st;
        float w  = aw * expf(rw);
        float h  = ah * expf(rh);
        float x1 = cx - 0.5f * w, y1 = cy - 0.5f * h;
        float x2 = cx + 0.5f * w, y2 = cy + 0.5f * h;

        float nx1 = fminf(fmaxf(x1 / IMGSZ, 0.0f), 1.0f);
        float ny1 = fminf(fmaxf(y1 / IMGSZ, 0.0f), 1.0f);
        float nx2 = fminf(fmaxf(x2 / IMGSZ, 0.0f), 1.0f);
        float ny2 = fminf(fmaxf(y2 / IMGSZ, 0.0f), 1.0f);

        float4 bx = make_float4(nx1, ny1, nx2, ny2);
        ((float4*)out_boxes)[b * NTOP + tid] = bx;
        ((float4*)nbox)[b * NPAD + tid]      = bx;
        nlab[b * NPAD + tid] = lab;
    }
}

// ---------------------------------------------------------------------------
// K4: suppression bit-matrix. 256-thr block per 64x64 tile; 4 waves, each
// wave owns 16 columns. lane = row i (box in regs); column box broadcast
// via __shfl (wave-uniform index); column word = __ballot(pred).
// Column area recomputed from broadcast components (bit-identical: broadcast
// is exact, expression unchanged). 16-iteration serial chain per wave.
// sup[b][tj][ti][j0]: bit ii set iff i=ti*64+ii suppresses j=tj*64+j0.
// ---------------------------------------------------------------------------
__global__ __launch_bounds__(256) void k_supmat(const float* __restrict__ nbox,
                                                const int* __restrict__ nlab,
                                                uint64_t* __restrict__ sup) {
#pragma clang fp contract(off)
    int b = blockIdx.y;
    int t = blockIdx.x;                 // 0..135 triangular pair index
    int tj = (int)((sqrtf(8.0f * (float)t + 1.0f) - 1.0f) * 0.5f);
    while ((tj + 1) * (tj + 2) / 2 <= t) ++tj;
    while (tj * (tj + 1) / 2 > t) --tj;
    int ti = t - tj * (tj + 1) / 2;

    int lane = threadIdx.x & 63;
    int w    = threadIdx.x >> 6;        // column quarter 0..3

    int i = ti * 64 + lane;             // row owned by this lane
    int j = tj * 64 + lane;             // column data this lane republishes

    float4 bi = ((const float4*)nbox)[b * NPAD + i];
    float  ai = (bi.z - bi.x) * (bi.w - bi.y);
    int    li = nlab[b * NPAD + i];
    float4 bj = ((const float4*)nbox)[b * NPAD + j];
    int    lj = nlab[b * NPAD + j];
    bool   iv = (i < NTOP);

    uint64_t mybits = 0;
#pragma unroll
    for (int u = 0; u < 16; ++u) {
        int jj = (w << 4) | u;          // wave-uniform column index
        float bjx = __shfl(bj.x, jj);
        float bjy = __shfl(bj.y, jj);
        float bjz = __shfl(bj.z, jj);
        float bjw = __shfl(bj.w, jj);
        int   ljv = __shfl(lj, jj);
        float ajv = (bjz - bjx) * (bjw - bjy);
        int   jg  = tj * 64 + jj;
        float xx1 = fmaxf(bi.x, bjx);
        float yy1 = fmaxf(bi.y, bjy);
        float xx2 = fminf(bi.z, bjz);
        float yy2 = fminf(bi.w, bjw);
        float inter = fmaxf(EPSF, xx2 - xx1) * fmaxf(EPSF, yy2 - yy1);
        float uni   = fmaxf(ai + ajv - inter, EPSF);
        float iou   = inter / uni;
        bool pred = (i < jg) && iv && (jg < NTOP) && (li == ljv) && (iou > NMS_TH);
        uint64_t bal = __ballot(pred);
        if (lane == jj) mybits = bal;
    }
    if ((lane >> 4) == w)
        sup[(((size_t)b * 16 + tj) * 16 + ti) * 64 + lane] = mybits;
}

// ---------------------------------------------------------------------------
// K5: greedy NMS scan, 16 waves per batch (wave w = column-block tj=w).
// ---------------------------------------------------------------------------
__global__ __launch_bounds__(1024) void k_nms(const float* __restrict__ out_scores,
                                              const uint64_t* __restrict__ sup,
                                              float* __restrict__ out_keep) {
    __shared__ uint64_t Kw[16];
    int b    = blockIdx.x;
    int w    = threadIdx.x >> 6;    // wave id = tj block
    int lane = threadIdx.x & 63;
    const uint64_t* supb = sup + (size_t)b * 16 * 16 * 64;

    uint64_t wrow[16];
#pragma unroll
    for (int ti = 0; ti < 16; ++ti)
        wrow[ti] = (ti <= w) ? supb[((size_t)w * 16 + ti) * 64 + lane] : 0ULL;

    int pos = w * 64 + lane;
    bool k0 = (pos < NTOP) && (out_scores[b * NTOP + pos] >= CONF_TH);

    uint64_t ext = 0;
#pragma unroll
    for (int s = 0; s < 16; ++s) {
        if (w == s) {
            bool cand = k0 && (ext == 0ULL);
            uint64_t wself = wrow[s];
            uint64_t alive = __ballot(cand);
            for (int it = 0; it < 64; ++it) {
                bool dead = (wself & alive) != 0ULL;
                uint64_t na = __ballot(cand && !dead);
                if (na == alive) break;
                alive = na;
            }
            if (lane == 0) Kw[s] = alive;
            if (pos < NTOP)
                out_keep[b * NTOP + pos] = ((alive >> lane) & 1ULL) ? 1.0f : 0.0f;
        }
        __syncthreads();
        if (w > s) ext |= wrow[s] & Kw[s];
    }
}

// ---------------------------------------------------------------------------
extern "C" void kernel_launch(void* const* d_in, const int* in_sizes, int n_in,
                              void* d_out, int out_size, void* d_ws, size_t ws_size,
                              hipStream_t stream) {
    const float* conf = (const float*)d_in[0];
    const float* cls  = (const float*)d_in[1];
    const float* reg  = (const float*)d_in[2];
    const float* anch = (const float*)d_in[3];
    const float* strm = (const float*)d_in[4];

    float* out        = (float*)d_out;
    float* out_scores = out;
    float* out_labels = out + NB * NTOP;
    float* out_boxes  = out + 2 * NB * NTOP;
    float* out_keep   = out + 2 * NB * NTOP + NB * NTOP * 4;

    char* ws = (char*)d_ws;
    float*    scores = (float*)(ws + OFF_SCORES);
    int*      labels = (int*)(ws + OFF_LABELS);
    float*    nbox   = (float*)(ws + OFF_NBOX);
    int*      nlab   = (int*)(ws + OFF_NLAB);
    uint64_t* sup    = (uint64_t*)(ws + OFF_SUP);

    k_score<<<(NB * NM * 16) / 256, 256, 0, stream>>>(conf, cls, scores, labels);
    k_topk<<<NB, BDT, 0, stream>>>(scores, labels, reg, anch, strm,
                                   out_scores, out_labels, out_boxes, nbox, nlab);
    k_supmat<<<dim3(136, NB), 256, 0, stream>>>(nbox, nlab, sup);
    k_nms<<<NB, 1024, 0, stream>>>(out_scores, sup, out_keep);
}